// Round 5
// baseline (240.681 us; speedup 1.0000x reference)
//
#include <hip/hip_runtime.h>
#include <hip/hip_bf16.h>

// out[b,o,hw] = sum_c W[o,c] * relu(x[b,c,hw]*scale[c] + shift[c])
// B=256, Cin=2112, Cout=192, HW=49, fp32 in HBM, bf16 MFMA internally.
//
// R12: BARRIER-FREE direct-gather GEMM. R8-R11 evidence: all pipes <20%
// busy at 8 waves/CU regardless of barrier count or wave grouping ->
// latency-bound lockstep. Fix: drop the LDS B-tile + staging + ALL
// barriers. Each wave gathers its own B-fragment straight from x
// (8 global_load_dword per granule; lanes 0-15 read 64B-contiguous, j*196
// fits the 13-bit imm offset), applies BN+ReLU in-register from an LDS
// float2 table (broadcast reads), and MFMAs. Software pipeline: parity-
// named prefetch buffers (xfE/O, bsE/O, arE/O), gather g+2 while MFMA g.
// Grid 512 = (b, Cout-half) x 8 waves -> 2 blocks/CU = 16 waves/CU of
// fully independent streams (was 8 lockstepped).
// Wave split: mg = wv&1 -> 48 rows (3 M-tiles), ng = wv>>1 -> 16 hw cols
// (ng=3 handles col 48 + discarded dups).

#define CIN    2112
#define COUT   192
#define HWS    49
#define BK     32
#define NK32   (CIN / BK)          // 66 granules
#define EPSV   1e-5f

typedef __bf16 bf16;
typedef __attribute__((ext_vector_type(8))) __bf16 bf16x8;
typedef __attribute__((ext_vector_type(4))) float  f32x4;

// ---------- kernel 1: W fp32 -> bf16 in A-fragment order (unchanged) ----------
__global__ __launch_bounds__(256)
void w_repack_kernel(const float* __restrict__ W, bf16* __restrict__ Wb) {
    const int t = blockIdx.x * 256 + threadIdx.x;       // 66*12*64 = 50688
    if (t >= NK32 * 12 * 64) return;
    const int lane = t & 63;
    const int gmt  = (t >> 6) % 12;
    const int ks   = t / (12 * 64);
    const int row  = gmt * 16 + (lane & 15);
    const int k    = ks * BK + (lane >> 4) * 8;
    const float* src = W + (size_t)row * CIN + k;
    f32x4 a = *(const f32x4*)src;
    f32x4 c = *(const f32x4*)(src + 4);
    bf16x8 o;
    #pragma unroll
    for (int j = 0; j < 4; j++) { o[j] = (bf16)a[j]; o[j + 4] = (bf16)c[j]; }
    *(bf16x8*)(Wb + (size_t)t * 8) = o;
}

// ---------- kernel 2: fused BN+ReLU+GEMM, barrier-free gather ----------
__global__ __launch_bounds__(512, 4)
void fused_kernel(const float* __restrict__ x,
                  const float* __restrict__ gamma,
                  const float* __restrict__ beta,
                  const float* __restrict__ rmean,
                  const float* __restrict__ rvar,
                  const bf16* __restrict__ Wb,
                  float* __restrict__ out)
{
    __shared__ float2 ss[CIN];                       // BN scale/shift

    const int tid = threadIdx.x;
    const int b   = blockIdx.x >> 1;                 // image
    const int mh  = blockIdx.x & 1;                  // Cout half (96 rows)

    // BN params -> LDS (one-time)
    for (int c = tid; c < CIN; c += 512) {
        float inv = rsqrtf(rvar[c] + EPSV);
        float s   = gamma[c] * inv;
        ss[c] = make_float2(s, beta[c] - rmean[c] * s);
    }

    const int lane = tid & 63;
    const int wv   = tid >> 6;         // 0..7
    const int mg   = wv & 1;           // 48-row group within the half
    const int ng   = wv >> 1;          // 0..3: 16-col hw slice
    const int l15  = lane & 15;
    const int q    = lane >> 4;        // 0..3: k-subgroup

    const int hwn = ng * 16 + l15;                   // 0..63
    const int hwc = (hwn < HWS) ? hwn : (HWS - 1);   // clamp; dups discarded

    // per-lane gather base: column hwc of image b
    const float* xb  = x + (size_t)b * (CIN * HWS) + hwc;
    const bf16*  apL = Wb + (size_t)(mh * 6 + mg * 3) * 512 + (size_t)lane * 8;

    f32x4 acc[3];
    #pragma unroll
    for (int mt = 0; mt < 3; mt++) acc[mt] = (f32x4)(0.f);

    // parity-named pipeline state (all statically indexed)
    float  xfE[8], xfO[8];
    float2 bsE[8], bsO[8];
    bf16x8 arE[3], arO[3];

    // A-frag preload for granules 0,1
    #pragma unroll
    for (int mt = 0; mt < 3; mt++) {
        arE[mt] = *(const bf16x8*)(apL + (size_t)(mt * 512));
        arO[mt] = *(const bf16x8*)(apL + (size_t)(6144 + mt * 512));
    }

    __syncthreads();   // ss ready (the ONLY barrier in this kernel)

    // x + BN preload for granules 0,1
    {
        const float* xp0 = xb + (size_t)(q * 8) * HWS;
        const float* xp1 = xb + (size_t)(BK + q * 8) * HWS;
        #pragma unroll
        for (int j = 0; j < 8; j++) xfE[j] = xp0[j * HWS];
        #pragma unroll
        for (int j = 0; j < 8; j++) xfO[j] = xp1[j * HWS];
        #pragma unroll
        for (int j = 0; j < 8; j++) bsE[j] = ss[q * 8 + j];
        #pragma unroll
        for (int j = 0; j < 8; j++) bsO[j] = ss[BK + q * 8 + j];
    }

    // one granule: build bfrag from (xf,bs); prefetch granule g+2 into the
    // same parity slots; 3 MFMA; prefetch A for g+2.
    auto STEP = [&](int g, float (&xf)[8], float2 (&bs)[8], bf16x8 (&ar)[3]) {
        bf16x8 bfrag;
        #pragma unroll
        for (int j = 0; j < 8; j++)
            bfrag[j] = (bf16)fmaxf(fmaf(xf[j], bs[j].x, bs[j].y), 0.f);

        int gn = g + 2; if (gn > NK32 - 1) gn = NK32 - 1;   // tail clamp
        const float* xp = xb + (size_t)(gn * BK + q * 8) * HWS;
        #pragma unroll
        for (int j = 0; j < 8; j++) xf[j] = xp[j * HWS];    // 8 gathers
        #pragma unroll
        for (int j = 0; j < 8; j++) bs[j] = ss[gn * BK + q * 8 + j];

        #pragma unroll
        for (int mt = 0; mt < 3; mt++)
            acc[mt] = __builtin_amdgcn_mfma_f32_16x16x32_bf16(ar[mt], bfrag, acc[mt], 0, 0, 0);

        const bf16* ap = apL + (size_t)gn * 6144;
        #pragma unroll
        for (int mt = 0; mt < 3; mt++)
            ar[mt] = *(const bf16x8*)(ap + (size_t)(mt * 512));
    };

    // rolled main loop, 33 parity pairs; no barriers, no LDS tile.
    #pragma unroll 1
    for (int it = 0; it < NK32 / 2; ++it) {
        STEP(2 * it,     xfE, bsE, arE);
        STEP(2 * it + 1, xfO, bsO, arO);
    }

    // epilogue: C/D col=l15 -> hw=hwn, row=q*4+r. Disjoint stores.
    if (hwn < HWS) {
        float* ob = out + (size_t)b * (COUT * HWS) + hwn;
        #pragma unroll
        for (int mt = 0; mt < 3; mt++) {
            const int row0 = (mh * 6 + mg * 3 + mt) * 16 + q * 4;
            #pragma unroll
            for (int r = 0; r < 4; r++)
                ob[(size_t)(row0 + r) * HWS] = acc[mt][r];
        }
    }
}

extern "C" void kernel_launch(void* const* d_in, const int* in_sizes, int n_in,
                              void* d_out, int out_size, void* d_ws, size_t ws_size,
                              hipStream_t stream) {
    const float* x     = (const float*)d_in[0];
    const float* gamma = (const float*)d_in[1];
    const float* beta  = (const float*)d_in[2];
    const float* rmean = (const float*)d_in[3];
    const float* rvar  = (const float*)d_in[4];
    const float* W     = (const float*)d_in[5];
    float* out = (float*)d_out;

    bf16* Wb = (bf16*)d_ws;                        // 811,008 B, L2-resident

    w_repack_kernel<<<dim3(198), dim3(256), 0, stream>>>(W, Wb);
    fused_kernel<<<dim3(512), dim3(512), 0, stream>>>(
        x, gamma, beta, rmean, rvar, Wb, out);
}